// Round 10
// baseline (115171.326 us; speedup 1.0000x reference)
//
#include <hip/hip_runtime.h>

// BiaffineParser round 10: flag-free LSTM sync via NaN-canary polling of the
// h data itself (memset 0xFF per layer; h never NaN). rel_k r-split x8.
// pre/heads/s_k/argmax unchanged (proven f64 + tau-window).

#define TT 128
#define HID 400
#define G4 1600
#define NTOK 8192
#define NWD 100     // workgroups per direction in lstm
#define CH 16       // timesteps per chunk
#define CAN 0xFFFFFFFFFFFFFFFFull

// ---------------- embedding concat (exact f32 copies) ----------------
__global__ void embed_k(const int* __restrict__ words, const int* __restrict__ pos,
                        const float* __restrict__ wemb, const float* __restrict__ pemb,
                        float* __restrict__ x0) {
    int m = blockIdx.x;            // m = t*64 + b
    int t = m >> 6, b = m & 63;
    int tid = threadIdx.x;
    if (tid < 100) {
        x0[(size_t)m * 125 + tid] = wemb[(size_t)words[b * TT + t] * 100 + tid];
    } else if (tid < 125) {
        x0[(size_t)m * 125 + tid] = pemb[(size_t)pos[b * TT + t] * 25 + (tid - 100)];
    }
}

// ---------------- dual-direction pre GEMM, 64x64 tiles, f64 (proven) ----------------
template <bool L0>
__global__ __launch_bounds__(256) void pre_k(
    const float* __restrict__ x0, const double* __restrict__ hF, const double* __restrict__ hB,
    const float* __restrict__ wiF, const float* __restrict__ wiB,
    const float* __restrict__ bF, const float* __restrict__ bB,
    double* __restrict__ prF, double* __restrict__ prB, int m0F, int m0B) {
    const int dir = blockIdx.z;
    const float* wi = dir ? wiB : wiF;
    const float* bias = dir ? bB : bF;
    double* pr = dir ? prB : prF;
    const int m0 = dir ? m0B : m0F;
    const int KP = L0 ? 128 : 800;

    __shared__ double As[16][66];   // [k][n]  <- wi
    __shared__ double Bs[16][66];   // [k][b]  <- h or x0

    const int tid = threadIdx.x;
    const int tm = tid >> 4, tn = tid & 15;
    const int bn = blockIdx.x * 64;
    const int y = blockIdx.y;
    const int tt = (m0 >> 6) + y;          // global timestep index
    const int lane = tid & 63, kq = tid >> 6;

    double acc[4][4];
#pragma unroll
    for (int i = 0; i < 4; i++)
#pragma unroll
        for (int j = 0; j < 4; j++) acc[i][j] = 0.0;

    for (int k0 = 0; k0 < KP; k0 += 16) {
        if (L0) {
#pragma unroll
            for (int u = 0; u < 4; u++) {
                int k = k0 + kq * 4 + u;
                As[kq * 4 + u][lane] = (k < 125) ? (double)wi[(size_t)(bn + lane) * 125 + k] : 0.0;
            }
        } else {
            const float4 wv = *(const float4*)&wi[(size_t)(bn + lane) * 800 + k0 + kq * 4];
            As[kq * 4 + 0][lane] = (double)wv.x;
            As[kq * 4 + 1][lane] = (double)wv.y;
            As[kq * 4 + 2][lane] = (double)wv.z;
            As[kq * 4 + 3][lane] = (double)wv.w;
        }
        if (L0) {
#pragma unroll
            for (int u = 0; u < 4; u++) {
                int k = k0 + kq * 4 + u;
                Bs[kq * 4 + u][lane] = (k < 125) ? (double)x0[((size_t)tt * 64 + lane) * 125 + k] : 0.0;
            }
        } else {
            int kbase = k0 + kq * 4;                // blocks of 4, never straddle 400
            const double* src = (kbase < 400) ? hF : hB;
            int kb = (kbase < 400) ? kbase : kbase - 400;
            const double* p = src + (size_t)tt * 25600 + (size_t)kb * 64 + lane;
#pragma unroll
            for (int u = 0; u < 4; u++) Bs[kq * 4 + u][lane] = p[(size_t)u * 64];
        }
        __syncthreads();
#pragma unroll
        for (int kk = 0; kk < 16; kk++) {
            double a[4], b[4];
#pragma unroll
            for (int i = 0; i < 4; i++) a[i] = As[kk][tm * 4 + i];
#pragma unroll
            for (int j = 0; j < 4; j++) b[j] = Bs[kk][tn * 4 + j];
#pragma unroll
            for (int i = 0; i < 4; i++)
#pragma unroll
                for (int j = 0; j < 4; j++) acc[i][j] = fma(a[i], b[j], acc[i][j]);
        }
        __syncthreads();
    }
#pragma unroll
    for (int i = 0; i < 4; i++) {
        int n = bn + tm * 4 + i;
        double bv = (double)bias[n];
#pragma unroll
        for (int j = 0; j < 4; j++)
            pr[((size_t)y * G4 + n) * 64 + (tn * 4 + j)] = acc[i][j] + bv;
    }
}

// ---------------- heads GEMM, 64x64 tiles, f64 accumulate (proven) ----------------
template <bool SPLITA, bool RELU, typename TC>
__global__ __launch_bounds__(256) void heads_k(
    const double* __restrict__ A, const double* __restrict__ AF, const double* __restrict__ AB,
    const float* __restrict__ Bm, const float* __restrict__ bias, TC* __restrict__ C,
    int N, int K, int ldb, int ldc, int OM) {
    __shared__ double As[16][66];   // [k][m]
    __shared__ double Bs[16][66];   // [k][n]
    const int tid = threadIdx.x;
    const int tm = tid >> 4, tn = tid & 15;
    const int bn = blockIdx.x * 64;
    const int bm = blockIdx.y * 64;
    const int lane = tid & 63, kq = tid >> 6;

    double acc[4][4];
#pragma unroll
    for (int i = 0; i < 4; i++)
#pragma unroll
        for (int j = 0; j < 4; j++) acc[i][j] = 0.0;

    const int KP = (K + 15) & ~15;
    for (int k0 = 0; k0 < KP; k0 += 16) {
        if (SPLITA) {
            int kbase = k0 + kq * 4;
            const double* src = (kbase < 400) ? AF : AB;
            int kb = (kbase < 400) ? kbase : kbase - 400;
            const double* p = src + (size_t)(bm >> 6) * 25600 + (size_t)kb * 64 + lane;
#pragma unroll
            for (int u = 0; u < 4; u++) As[kq * 4 + u][lane] = p[(size_t)u * 64];
        } else {
#pragma unroll
            for (int u = 0; u < 4; u++) {
                int k = k0 + kq * 4 + u;
                As[kq * 4 + u][lane] = (k < K) ? A[(size_t)(bm + lane) * K + k] : 0.0;
            }
        }
        {
            bool nok = (bn + lane) < N;
#pragma unroll
            for (int u = 0; u < 4; u++) {
                int k = k0 + kq * 4 + u;
                Bs[kq * 4 + u][lane] = (nok && k < K) ? (double)Bm[(size_t)k * ldb + bn + lane] : 0.0;
            }
        }
        __syncthreads();
#pragma unroll
        for (int kk = 0; kk < 16; kk++) {
            double a[4], b[4];
#pragma unroll
            for (int i = 0; i < 4; i++) a[i] = As[kk][tm * 4 + i];
#pragma unroll
            for (int j = 0; j < 4; j++) b[j] = Bs[kk][tn * 4 + j];
#pragma unroll
            for (int i = 0; i < 4; i++)
#pragma unroll
                for (int j = 0; j < 4; j++) acc[i][j] = fma(a[i], b[j], acc[i][j]);
        }
        __syncthreads();
    }
#pragma unroll
    for (int i = 0; i < 4; i++) {
        int row = bm + tm * 4 + i;
        size_t orow = (OM == 0) ? (size_t)row
                                : ((size_t)(row & 63) * TT + (row >> 6));
#pragma unroll
        for (int j = 0; j < 4; j++) {
            int n = bn + tn * 4 + j;
            if (n >= N) continue;
            double v = acc[i][j] + (bias ? (double)bias[n] : 0.0);
            if (RELU) v = fmax(v, 0.0);
            C[orow * ldc + n] = (TC)v;
        }
    }
}

// ---------------- both-direction LSTM chunk (f64), canary-poll sync ----------------
// 200 WGs x 512 threads. h buffers pre-filled with 0xFF (f64 NaN) per layer;
// consumers poll their own h loads until non-canary (h is never NaN). No flags,
// no fences: each h location is written exactly once.
__global__ __launch_bounds__(512) void lstm_k(
    const double* __restrict__ preF, const double* __restrict__ preB,
    const float* __restrict__ whF, const float* __restrict__ whB,
    double* __restrict__ hsF, double* __restrict__ hsB,
    double* __restrict__ csF, double* __restrict__ csB, int ci) {
    const int wg = blockIdx.x;
    const int dir = wg / NWD;
    const int wgd = wg % NWD;
    const double* pre = dir ? preB : preF;
    const float* wh = dir ? whB : whF;
    double* hs = dir ? hsB : hsF;
    double* cs = dir ? csB : csF;
    const int tid = threadIdx.x;
    const int b = tid & 63;
    const int w = tid >> 6;
    const int tlb = dir ? (TT - CH - ci * CH) : ci * CH;

    __shared__ double whl[4][HID][4];
    __shared__ double pl[8][4][4][64];
    for (int idx = tid; idx < 4 * HID * 4; idx += 512) {
        int g = idx & 3; int k = (idx >> 2) % HID; int jx = idx / (4 * HID);
        whl[jx][k][g] = (double)wh[((size_t)g * HID + wgd * 4 + jx) * HID + k];
    }
    __syncthreads();

    const int jown = wgd * 4 + (w & 3);
    double c = 0.0;
    if (w < 4) c = (ci == 0) ? 0.0 : cs[(size_t)jown * 64 + b];

    for (int s = 0; s < CH; ++s) {
        const int sg = ci * CH + s;
        const int t = dir ? (TT - 1 - sg) : sg;
        // pre loads are independent of h: issue early (finalizer threads only)
        double z0[4];
        if (w < 4) {
            const double* pp = pre + (size_t)(t - tlb) * (G4 * 64) + b;
#pragma unroll
            for (int g = 0; g < 4; g++) z0[g] = pp[(size_t)(g * HID + jown) * 64];
        }
        double part[4][4];
#pragma unroll
        for (int j = 0; j < 4; j++)
#pragma unroll
            for (int g = 0; g < 4; g++) part[j][g] = 0.0;
        if (sg > 0) {
            const int tp = dir ? (t + 1) : (t - 1);
            const unsigned long long* hp =
                (const unsigned long long*)(hs + (size_t)tp * (HID * 64) + b);
            const int k0 = w * 50;
#pragma unroll
            for (int g4 = 0; g4 < 5; ++g4) {
                unsigned long long v[10];
#pragma unroll
                for (int u = 0; u < 10; u++)
                    v[u] = __hip_atomic_load(&hp[(size_t)(k0 + g4 * 10 + u) * 64],
                                             __ATOMIC_RELAXED, __HIP_MEMORY_SCOPE_AGENT);
                for (;;) {
                    bool again = false;
#pragma unroll
                    for (int u = 0; u < 10; u++) {
                        if (v[u] == CAN) {
                            v[u] = __hip_atomic_load(&hp[(size_t)(k0 + g4 * 10 + u) * 64],
                                                     __ATOMIC_RELAXED, __HIP_MEMORY_SCOPE_AGENT);
                            if (v[u] == CAN) again = true;
                        }
                    }
                    if (!again) break;
                }
#pragma unroll
                for (int u = 0; u < 10; u++) {
                    double hv = __builtin_bit_cast(double, v[u]);
                    int k = k0 + g4 * 10 + u;
#pragma unroll
                    for (int j = 0; j < 4; j++)
#pragma unroll
                        for (int g = 0; g < 4; g++)
                            part[j][g] = fma(hv, whl[j][k][g], part[j][g]);
                }
            }
        }
#pragma unroll
        for (int j = 0; j < 4; j++)
#pragma unroll
            for (int g = 0; g < 4; g++) pl[w][j][g][b] = part[j][g];
        __syncthreads();
        if (w < 4) {
            double z[4];
#pragma unroll
            for (int g = 0; g < 4; g++) {
                double acc = z0[g];
#pragma unroll
                for (int q = 0; q < 8; q++) acc += pl[q][w][g][b];
                z[g] = acc;
            }
            double si = 1.0 / (1.0 + exp(-z[0]));
            double sf = 1.0 / (1.0 + exp(-z[1]));
            double tg = tanh(z[2]);
            double so = 1.0 / (1.0 + exp(-z[3]));
            c = sf * c + si * tg;
            double h = so * tanh(c);
            __hip_atomic_store(&hs[(size_t)t * (HID * 64) + (size_t)jown * 64 + b], h,
                               __ATOMIC_RELAXED, __HIP_MEMORY_SCOPE_AGENT);
        }
        __syncthreads();   // pl reuse guard
    }
    if (w < 4) cs[(size_t)jown * 64 + b] = c;
}

// ---------------- b_arc . H_ah[b,j] (f64) ----------------
__global__ void bh_k(const double* __restrict__ Hah, const float* __restrict__ barc,
                     double* __restrict__ bh) {
    int row = blockIdx.x * 4 + (threadIdx.x >> 6);
    int lane = threadIdx.x & 63;
    const double* r = Hah + (size_t)row * 500;
    double s = 0.0;
    for (int e = lane; e < 500; e += 64) s = fma(r[e], (double)barc[e], s);
    for (int off = 32; off; off >>= 1) s += __shfl_down(s, off, 64);
    if (lane == 0) bh[row] = s;
}

// ---------------- biaffine scores (f64), write S64 + f32 S ----------------
__global__ __launch_bounds__(256) void s_k(const double* __restrict__ HadW,
                                           const double* __restrict__ Hah,
                                           const double* __restrict__ bh,
                                           double* __restrict__ S64,
                                           float* __restrict__ Sf) {
    int b = blockIdx.z;
    int i = blockIdx.y * 16 + threadIdx.y;
    int j = blockIdx.x * 16 + threadIdx.x;
    const double* ra = HadW + ((size_t)b * TT + i) * 500;
    const double* rb = Hah + ((size_t)b * TT + j) * 500;
    double s = 0.0;
#pragma unroll 4
    for (int e = 0; e < 500; ++e) s = fma(ra[e], rb[e], s);
    double v = s + bh[b * TT + j];
    size_t o = ((size_t)b * TT + i) * TT + j;
    S64[o] = v;
    Sf[o] = (float)v;
}

// ---------------- argmax with near-tie window, first-index pref ----------------
__global__ void argmax_k(const double* __restrict__ S64, int* __restrict__ headi,
                         float* __restrict__ headf) {
    int row = blockIdx.x * 4 + (threadIdx.x >> 6);
    int lane = threadIdx.x & 63;
    const double* r = S64 + (size_t)row * TT;
    double v0 = r[lane], v1 = r[lane + 64];
    double m = fmax(v0, v1);
    for (int off = 32; off; off >>= 1) m = fmax(m, __shfl_down(m, off, 64));
    m = __shfl(m, 0, 64);
    double tau = 1e-4 + 3e-6 * fabs(m);
    int c = 999;
    if (v1 >= m - tau) c = lane + 64;
    if (v0 >= m - tau) c = lane;
    for (int off = 32; off; off >>= 1) {
        int oc = __shfl_down(c, off, 64);
        c = min(c, oc);
    }
    if (lane == 0) { headi[row] = c; headf[row] = (float)c; }
}

// ---------------- rel scores: f32, 8-chain ILP, r-split x8 ----------------
__global__ __launch_bounds__(320) void rel_k(
    const float* __restrict__ Hrh, const float* __restrict__ Hrd,
    const int* __restrict__ headi, const float* __restrict__ U,
    const float* __restrict__ Wrel, const float* __restrict__ brel,
    float* __restrict__ out) {
    __shared__ float sel[32][105];
    __shared__ float rd[32][105];
    __shared__ float red[32][12];
    int tid = threadIdx.x;
    int blk = blockIdx.x;
    for (int idx = tid; idx < 32 * 100; idx += 320) {
        int tt2 = idx / 100, d = idx % 100;
        int tok = blk * 32 + tt2;
        int b = tok >> 7;
        int hp = headi[tok] & 127;
        sel[tt2][d] = Hrh[((size_t)(b << 7) + hp) * 100 + d];
        rd[tt2][d] = Hrd[(size_t)tok * 100 + d];
    }
    __syncthreads();
    int tt2 = tid & 31;
    int dg = tid >> 5;   // 0..9
    int tok = blk * 32 + tt2;
    int r0 = blockIdx.y * 6;
    int r1 = min(46, r0 + 6);
    for (int r = r0; r < r1; ++r) {
        float acc = 0.f;
#pragma unroll
        for (int dd = 0; dd < 10; dd += 2) {
            int d = dg * 10 + dd;
            const float4* uA = (const float4*)(U + ((size_t)d * 46 + r) * 100);
            const float4* uB = (const float4*)(U + ((size_t)(d + 1) * 46 + r) * 100);
            float a0 = 0.f, a1 = 0.f, a2 = 0.f, a3 = 0.f;
            float b0 = 0.f, b1 = 0.f, b2 = 0.f, b3 = 0.f;
#pragma unroll
            for (int q = 0; q < 25; ++q) {
                float4 ua = uA[q], ub = uB[q];
                float r0v = rd[tt2][4 * q + 0], r1v = rd[tt2][4 * q + 1];
                float r2v = rd[tt2][4 * q + 2], r3v = rd[tt2][4 * q + 3];
                a0 = fmaf(ua.x, r0v, a0); a1 = fmaf(ua.y, r1v, a1);
                a2 = fmaf(ua.z, r2v, a2); a3 = fmaf(ua.w, r3v, a3);
                b0 = fmaf(ub.x, r0v, b0); b1 = fmaf(ub.y, r1v, b1);
                b2 = fmaf(ub.z, r2v, b2); b3 = fmaf(ub.w, r3v, b3);
            }
            acc = fmaf(sel[tt2][d], (a0 + a1) + (a2 + a3), acc);
            acc = fmaf(sel[tt2][d + 1], (b0 + b1) + (b2 + b3), acc);
        }
        if (dg == 0) {
            float sdot = 0.f;
#pragma unroll 4
            for (int k = 0; k < 100; ++k)
                sdot = fmaf(sel[tt2][k] + rd[tt2][k], Wrel[k * 46 + r], sdot);
            acc += sdot + brel[r];
        }
        red[tt2][dg] = acc;
        __syncthreads();
        if (dg == 0) {
            float tot = 0.f;
#pragma unroll
            for (int q = 0; q < 10; ++q) tot += red[tt2][q];
            out[(size_t)tok * 46 + r] = tot;
        }
        __syncthreads();
    }
}

// ---------------- launch ----------------
extern "C" void kernel_launch(void* const* d_in, const int* in_sizes, int n_in,
                              void* d_out, int out_size, void* d_ws, size_t ws_size,
                              hipStream_t stream) {
    const float* wemb = (const float*)d_in[0];
    const float* pemb = (const float*)d_in[1];
    const float* wi[3][2] = {{(const float*)d_in[2], (const float*)d_in[5]},
                             {(const float*)d_in[8], (const float*)d_in[11]},
                             {(const float*)d_in[14], (const float*)d_in[17]}};
    const float* wh[3][2] = {{(const float*)d_in[3], (const float*)d_in[6]},
                             {(const float*)d_in[9], (const float*)d_in[12]},
                             {(const float*)d_in[15], (const float*)d_in[18]}};
    const float* bia[3][2] = {{(const float*)d_in[4], (const float*)d_in[7]},
                              {(const float*)d_in[10], (const float*)d_in[13]},
                              {(const float*)d_in[16], (const float*)d_in[19]}};
    const float* Wad = (const float*)d_in[20]; const float* bad = (const float*)d_in[21];
    const float* Wah = (const float*)d_in[22]; const float* bah = (const float*)d_in[23];
    const float* Wrd = (const float*)d_in[24]; const float* brd = (const float*)d_in[25];
    const float* Wrh = (const float*)d_in[26]; const float* brh = (const float*)d_in[27];
    const float* Warc = (const float*)d_in[28]; const float* barc = (const float*)d_in[29];
    const float* U = (const float*)d_in[30];
    const float* Wrel = (const float*)d_in[31]; const float* brel = (const float*)d_in[32];
    const int* words = (const int*)d_in[33];
    const int* pos = (const int*)d_in[34];

    // ---- workspace (bytes); peak 133,005,312 ----
    char* ws = (char*)d_ws;
    double* hsA  = (double*)(ws + 0);
    double* hsB  = (double*)(ws + 52428800);
    float*  x0   = (float*)(ws + 52428800);      // aliases hsB (dead before layer-1 canary)
    double* preF = (double*)(ws + 104857600);
    double* preB = (double*)(ws + 117964800);
    double* csF  = (double*)(ws + 131072000);    // 204,800
    double* csB  = (double*)(ws + 131276800);    // 204,800 -> ends 131,481,600
    double* Hah64  = (double*)(ws + 52428800);
    double* Had64  = (double*)(ws + 85196800);
    float*  Hrh    = (float*)(ws + 117964800);
    float*  Hrd    = (float*)(ws + 121241600);
    double* S64    = (double*)(ws + 124518400);
    double* bh64   = (double*)(ws + 132907008);
    int*    headi  = (int*)(ws + 132972544);
    double* HadW64 = (double*)(ws + 0);          // over hsA (dead after head GEMMs)

    float* Sf = (float*)d_out;
    float* rel = Sf + 1048576;
    float* headf = Sf + 1425408;

    embed_k<<<NTOK, 128, 0, stream>>>(words, pos, wemb, pemb, x0);

    const size_t HALF = 3276800;   // doubles per direction (128*400*64)
    const size_t HBYTES = 52428800;
    dim3 gPre(25, CH, 2);
    for (int l = 0; l < 3; ++l) {
        double* ho = (l == 1) ? hsB : hsA;
        const double* hiF = (l == 0) ? nullptr : ((l == 1) ? hsA : hsB);
        const double* hiB = hiF ? hiF + HALF : nullptr;
        hipMemsetAsync(ho, 0xFF, HBYTES, stream);   // canary-fill h output buffer
        for (int ci = 0; ci < 8; ++ci) {
            int m0F = ci * CH * 64;
            int m0B = (TT - CH - ci * CH) * 64;
            if (l == 0)
                pre_k<true><<<gPre, 256, 0, stream>>>(x0, nullptr, nullptr,
                    wi[0][0], wi[0][1], bia[0][0], bia[0][1], preF, preB, m0F, m0B);
            else
                pre_k<false><<<gPre, 256, 0, stream>>>(nullptr, hiF, hiB,
                    wi[l][0], wi[l][1], bia[l][0], bia[l][1], preF, preB, m0F, m0B);
            lstm_k<<<2 * NWD, 512, 0, stream>>>(preF, preB, wh[l][0], wh[l][1],
                ho, ho + HALF, csF, csB, ci);
        }
    }
    // heads from final h (hsA)
    const double* fF = hsA; const double* fB = hsA + HALF;
    heads_k<true, true, double><<<dim3(8, 128), 256, 0, stream>>>(
        nullptr, fF, fB, Wah, bah, Hah64, 500, 800, 500, 500, 1);
    heads_k<true, true, double><<<dim3(8, 128), 256, 0, stream>>>(
        nullptr, fF, fB, Wad, bad, Had64, 500, 800, 500, 500, 0);
    heads_k<true, true, float><<<dim3(2, 128), 256, 0, stream>>>(
        nullptr, fF, fB, Wrh, brh, Hrh, 100, 800, 100, 100, 1);
    heads_k<true, true, float><<<dim3(2, 128), 256, 0, stream>>>(
        nullptr, fF, fB, Wrd, brd, Hrd, 100, 800, 100, 100, 1);
    // hsA dead now; HadW64 aliases it
    heads_k<false, false, double><<<dim3(8, 128), 256, 0, stream>>>(
        Had64, nullptr, nullptr, Warc, nullptr, HadW64, 500, 500, 500, 500, 1);

    bh_k<<<NTOK / 4, 256, 0, stream>>>(Hah64, barc, bh64);
    s_k<<<dim3(8, 8, 64), dim3(16, 16), 0, stream>>>(HadW64, Hah64, bh64, S64, Sf);
    argmax_k<<<NTOK / 4, 256, 0, stream>>>(S64, headi, headf);
    rel_k<<<dim3(NTOK / 32, 8), 320, 0, stream>>>(Hrh, Hrd, headi, U, Wrel, brel, rel);
}

// Round 11
// 11463.756 us; speedup vs baseline: 10.0466x; 10.0466x over previous
//
#include <hip/hip_runtime.h>

// BiaffineParser round 11: round-9 base (proven, 11.76 ms); lstm h exchange =
// write-through atomic stores + PLAIN CACHED loads (LLC-served, no HBM
// redundancy). Flags + workgroup acquire fence; z0 pre-loads hoisted.

#define TT 128
#define HID 400
#define G4 1600
#define NTOK 8192
#define NWD 100     // workgroups per direction in lstm
#define CH 16       // timesteps per chunk

// ---------------- embedding concat (exact f32 copies) ----------------
__global__ void embed_k(const int* __restrict__ words, const int* __restrict__ pos,
                        const float* __restrict__ wemb, const float* __restrict__ pemb,
                        float* __restrict__ x0) {
    int m = blockIdx.x;            // m = t*64 + b
    int t = m >> 6, b = m & 63;
    int tid = threadIdx.x;
    if (tid < 100) {
        x0[(size_t)m * 125 + tid] = wemb[(size_t)words[b * TT + t] * 100 + tid];
    } else if (tid < 125) {
        x0[(size_t)m * 125 + tid] = pemb[(size_t)pos[b * TT + t] * 25 + (tid - 100)];
    }
}

// ---------------- dual-direction pre GEMM, 64x64 tiles, f64 (proven) ----------------
template <bool L0>
__global__ __launch_bounds__(256) void pre_k(
    const float* __restrict__ x0, const double* __restrict__ hF, const double* __restrict__ hB,
    const float* __restrict__ wiF, const float* __restrict__ wiB,
    const float* __restrict__ bF, const float* __restrict__ bB,
    double* __restrict__ prF, double* __restrict__ prB, int m0F, int m0B) {
    const int dir = blockIdx.z;
    const float* wi = dir ? wiB : wiF;
    const float* bias = dir ? bB : bF;
    double* pr = dir ? prB : prF;
    const int m0 = dir ? m0B : m0F;
    const int KP = L0 ? 128 : 800;

    __shared__ double As[16][66];   // [k][n]  <- wi
    __shared__ double Bs[16][66];   // [k][b]  <- h or x0

    const int tid = threadIdx.x;
    const int tm = tid >> 4, tn = tid & 15;
    const int bn = blockIdx.x * 64;
    const int y = blockIdx.y;
    const int tt = (m0 >> 6) + y;          // global timestep index
    const int lane = tid & 63, kq = tid >> 6;

    double acc[4][4];
#pragma unroll
    for (int i = 0; i < 4; i++)
#pragma unroll
        for (int j = 0; j < 4; j++) acc[i][j] = 0.0;

    for (int k0 = 0; k0 < KP; k0 += 16) {
        if (L0) {
#pragma unroll
            for (int u = 0; u < 4; u++) {
                int k = k0 + kq * 4 + u;
                As[kq * 4 + u][lane] = (k < 125) ? (double)wi[(size_t)(bn + lane) * 125 + k] : 0.0;
            }
        } else {
            const float4 wv = *(const float4*)&wi[(size_t)(bn + lane) * 800 + k0 + kq * 4];
            As[kq * 4 + 0][lane] = (double)wv.x;
            As[kq * 4 + 1][lane] = (double)wv.y;
            As[kq * 4 + 2][lane] = (double)wv.z;
            As[kq * 4 + 3][lane] = (double)wv.w;
        }
        if (L0) {
#pragma unroll
            for (int u = 0; u < 4; u++) {
                int k = k0 + kq * 4 + u;
                Bs[kq * 4 + u][lane] = (k < 125) ? (double)x0[((size_t)tt * 64 + lane) * 125 + k] : 0.0;
            }
        } else {
            int kbase = k0 + kq * 4;                // blocks of 4, never straddle 400
            const double* src = (kbase < 400) ? hF : hB;
            int kb = (kbase < 400) ? kbase : kbase - 400;
            const double* p = src + (size_t)tt * 25600 + (size_t)kb * 64 + lane;
#pragma unroll
            for (int u = 0; u < 4; u++) Bs[kq * 4 + u][lane] = p[(size_t)u * 64];
        }
        __syncthreads();
#pragma unroll
        for (int kk = 0; kk < 16; kk++) {
            double a[4], b[4];
#pragma unroll
            for (int i = 0; i < 4; i++) a[i] = As[kk][tm * 4 + i];
#pragma unroll
            for (int j = 0; j < 4; j++) b[j] = Bs[kk][tn * 4 + j];
#pragma unroll
            for (int i = 0; i < 4; i++)
#pragma unroll
                for (int j = 0; j < 4; j++) acc[i][j] = fma(a[i], b[j], acc[i][j]);
        }
        __syncthreads();
    }
#pragma unroll
    for (int i = 0; i < 4; i++) {
        int n = bn + tm * 4 + i;
        double bv = (double)bias[n];
#pragma unroll
        for (int j = 0; j < 4; j++)
            pr[((size_t)y * G4 + n) * 64 + (tn * 4 + j)] = acc[i][j] + bv;
    }
}

// ---------------- heads GEMM, 64x64 tiles, f64 accumulate (proven) ----------------
template <bool SPLITA, bool RELU, typename TC>
__global__ __launch_bounds__(256) void heads_k(
    const double* __restrict__ A, const double* __restrict__ AF, const double* __restrict__ AB,
    const float* __restrict__ Bm, const float* __restrict__ bias, TC* __restrict__ C,
    int N, int K, int ldb, int ldc, int OM) {
    __shared__ double As[16][66];   // [k][m]
    __shared__ double Bs[16][66];   // [k][n]
    const int tid = threadIdx.x;
    const int tm = tid >> 4, tn = tid & 15;
    const int bn = blockIdx.x * 64;
    const int bm = blockIdx.y * 64;
    const int lane = tid & 63, kq = tid >> 6;

    double acc[4][4];
#pragma unroll
    for (int i = 0; i < 4; i++)
#pragma unroll
        for (int j = 0; j < 4; j++) acc[i][j] = 0.0;

    const int KP = (K + 15) & ~15;
    for (int k0 = 0; k0 < KP; k0 += 16) {
        if (SPLITA) {
            int kbase = k0 + kq * 4;
            const double* src = (kbase < 400) ? AF : AB;
            int kb = (kbase < 400) ? kbase : kbase - 400;
            const double* p = src + (size_t)(bm >> 6) * 25600 + (size_t)kb * 64 + lane;
#pragma unroll
            for (int u = 0; u < 4; u++) As[kq * 4 + u][lane] = p[(size_t)u * 64];
        } else {
#pragma unroll
            for (int u = 0; u < 4; u++) {
                int k = k0 + kq * 4 + u;
                As[kq * 4 + u][lane] = (k < K) ? A[(size_t)(bm + lane) * K + k] : 0.0;
            }
        }
        {
            bool nok = (bn + lane) < N;
#pragma unroll
            for (int u = 0; u < 4; u++) {
                int k = k0 + kq * 4 + u;
                Bs[kq * 4 + u][lane] = (nok && k < K) ? (double)Bm[(size_t)k * ldb + bn + lane] : 0.0;
            }
        }
        __syncthreads();
#pragma unroll
        for (int kk = 0; kk < 16; kk++) {
            double a[4], b[4];
#pragma unroll
            for (int i = 0; i < 4; i++) a[i] = As[kk][tm * 4 + i];
#pragma unroll
            for (int j = 0; j < 4; j++) b[j] = Bs[kk][tn * 4 + j];
#pragma unroll
            for (int i = 0; i < 4; i++)
#pragma unroll
                for (int j = 0; j < 4; j++) acc[i][j] = fma(a[i], b[j], acc[i][j]);
        }
        __syncthreads();
    }
#pragma unroll
    for (int i = 0; i < 4; i++) {
        int row = bm + tm * 4 + i;
        size_t orow = (OM == 0) ? (size_t)row
                                : ((size_t)(row & 63) * TT + (row >> 6));
#pragma unroll
        for (int j = 0; j < 4; j++) {
            int n = bn + tn * 4 + j;
            if (n >= N) continue;
            double v = acc[i][j] + (bias ? (double)bias[n] : 0.0);
            if (RELU) v = fmax(v, 0.0);
            C[orow * ldc + n] = (TC)v;
        }
    }
}

// ---------------- both-direction LSTM chunk (f64), flags + cached h reads ----
// Producers: write-through (agent relaxed atomic) h stores -> LLC; flag release
// after syncthreads drain. Consumers: poll flags, workgroup acquire fence,
// then PLAIN CACHED h loads (each h address first-touched once per launch,
// so no stale lines; LLC serves cross-XCD).
__global__ __launch_bounds__(512) void lstm_k(
    const double* __restrict__ preF, const double* __restrict__ preB,
    const float* __restrict__ whF, const float* __restrict__ whB,
    double* __restrict__ hsF, double* __restrict__ hsB,
    double* __restrict__ csF, double* __restrict__ csB,
    int* __restrict__ flagsF, int* __restrict__ flagsB, int ci) {
    const int wg = blockIdx.x;
    const int dir = wg / NWD;
    const int wgd = wg % NWD;
    const double* pre = dir ? preB : preF;
    const float* wh = dir ? whB : whF;
    double* hs = dir ? hsB : hsF;
    double* cs = dir ? csB : csF;
    int* flags = dir ? flagsB : flagsF;
    const int tid = threadIdx.x;
    const int b = tid & 63;
    const int w = tid >> 6;
    const int tlb = dir ? (TT - CH - ci * CH) : ci * CH;

    __shared__ double whl[4][HID][4];
    __shared__ double pl[8][4][4][64];
    for (int idx = tid; idx < 4 * HID * 4; idx += 512) {
        int g = idx & 3; int k = (idx >> 2) % HID; int jx = idx / (4 * HID);
        whl[jx][k][g] = (double)wh[((size_t)g * HID + wgd * 4 + jx) * HID + k];
    }
    __syncthreads();

    const int jown = wgd * 4 + (w & 3);
    double c = 0.0;
    if (w < 4) c = (ci == 0) ? 0.0 : cs[(size_t)jown * 64 + b];

    for (int s = 0; s < CH; ++s) {
        const int sg = ci * CH + s;
        const int t = dir ? (TT - 1 - sg) : sg;
        // pre loads independent of h: issue before the poll
        double z0[4];
        if (w < 4) {
            const double* pp = pre + (size_t)(t - tlb) * (G4 * 64) + b;
#pragma unroll
            for (int g = 0; g < 4; g++) z0[g] = pp[(size_t)(g * HID + jown) * 64];
        }
        if (sg > 0) {
            bool need2 = b < (NWD - 64);
            for (;;) {
                int f1 = __hip_atomic_load(&flags[b], __ATOMIC_RELAXED, __HIP_MEMORY_SCOPE_AGENT);
                int f2 = need2 ? __hip_atomic_load(&flags[64 + b], __ATOMIC_RELAXED, __HIP_MEMORY_SCOPE_AGENT)
                               : 0x7fffffff;
                if (__all(f1 >= sg && f2 >= sg)) break;
                __builtin_amdgcn_s_sleep(1);
            }
            __builtin_amdgcn_fence(__ATOMIC_ACQUIRE, "workgroup");
        }
        double part[4][4];
#pragma unroll
        for (int j = 0; j < 4; j++)
#pragma unroll
            for (int g = 0; g < 4; g++) part[j][g] = 0.0;
        if (sg > 0) {
            const int tp = dir ? (t + 1) : (t - 1);
            const double* hp = hs + (size_t)tp * (HID * 64) + b;
#pragma unroll 5
            for (int k = w * 50; k < w * 50 + 50; ++k) {
                double hv = hp[(size_t)k * 64];     // plain cached load (LLC-served)
#pragma unroll
                for (int j = 0; j < 4; j++)
#pragma unroll
                    for (int g = 0; g < 4; g++)
                        part[j][g] = fma(hv, whl[j][k][g], part[j][g]);
            }
        }
#pragma unroll
        for (int j = 0; j < 4; j++)
#pragma unroll
            for (int g = 0; g < 4; g++) pl[w][j][g][b] = part[j][g];
        __syncthreads();
        if (w < 4) {
            double z[4];
#pragma unroll
            for (int g = 0; g < 4; g++) {
                double acc = z0[g];
#pragma unroll
                for (int q = 0; q < 8; q++) acc += pl[q][w][g][b];
                z[g] = acc;
            }
            double si = 1.0 / (1.0 + exp(-z[0]));
            double sf = 1.0 / (1.0 + exp(-z[1]));
            double tg = tanh(z[2]);
            double so = 1.0 / (1.0 + exp(-z[3]));
            c = sf * c + si * tg;
            double h = so * tanh(c);
            __hip_atomic_store(&hs[(size_t)t * (HID * 64) + (size_t)jown * 64 + b], h,
                               __ATOMIC_RELAXED, __HIP_MEMORY_SCOPE_AGENT);
        }
        __syncthreads();   // drains h stores (vmcnt0) + pl reuse guard
        if (tid == 0)
            __hip_atomic_store(&flags[wgd], sg + 1, __ATOMIC_RELEASE, __HIP_MEMORY_SCOPE_AGENT);
    }
    if (w < 4) cs[(size_t)jown * 64 + b] = c;
}

// ---------------- b_arc . H_ah[b,j] (f64) ----------------
__global__ void bh_k(const double* __restrict__ Hah, const float* __restrict__ barc,
                     double* __restrict__ bh) {
    int row = blockIdx.x * 4 + (threadIdx.x >> 6);
    int lane = threadIdx.x & 63;
    const double* r = Hah + (size_t)row * 500;
    double s = 0.0;
    for (int e = lane; e < 500; e += 64) s = fma(r[e], (double)barc[e], s);
    for (int off = 32; off; off >>= 1) s += __shfl_down(s, off, 64);
    if (lane == 0) bh[row] = s;
}

// ---------------- biaffine scores (f64), write S64 + f32 S ----------------
__global__ __launch_bounds__(256) void s_k(const double* __restrict__ HadW,
                                           const double* __restrict__ Hah,
                                           const double* __restrict__ bh,
                                           double* __restrict__ S64,
                                           float* __restrict__ Sf) {
    int b = blockIdx.z;
    int i = blockIdx.y * 16 + threadIdx.y;
    int j = blockIdx.x * 16 + threadIdx.x;
    const double* ra = HadW + ((size_t)b * TT + i) * 500;
    const double* rb = Hah + ((size_t)b * TT + j) * 500;
    double s = 0.0;
#pragma unroll 4
    for (int e = 0; e < 500; ++e) s = fma(ra[e], rb[e], s);
    double v = s + bh[b * TT + j];
    size_t o = ((size_t)b * TT + i) * TT + j;
    S64[o] = v;
    Sf[o] = (float)v;
}

// ---------------- argmax with near-tie window, first-index pref ----------------
__global__ void argmax_k(const double* __restrict__ S64, int* __restrict__ headi,
                         float* __restrict__ headf) {
    int row = blockIdx.x * 4 + (threadIdx.x >> 6);
    int lane = threadIdx.x & 63;
    const double* r = S64 + (size_t)row * TT;
    double v0 = r[lane], v1 = r[lane + 64];
    double m = fmax(v0, v1);
    for (int off = 32; off; off >>= 1) m = fmax(m, __shfl_down(m, off, 64));
    m = __shfl(m, 0, 64);
    double tau = 1e-4 + 3e-6 * fabs(m);
    int c = 999;
    if (v1 >= m - tau) c = lane + 64;
    if (v0 >= m - tau) c = lane;
    for (int off = 32; off; off >>= 1) {
        int oc = __shfl_down(c, off, 64);
        c = min(c, oc);
    }
    if (lane == 0) { headi[row] = c; headf[row] = (float)c; }
}

// ---------------- rel scores: f32, 8-chain ILP, r-split x8 ----------------
__global__ __launch_bounds__(320) void rel_k(
    const float* __restrict__ Hrh, const float* __restrict__ Hrd,
    const int* __restrict__ headi, const float* __restrict__ U,
    const float* __restrict__ Wrel, const float* __restrict__ brel,
    float* __restrict__ out) {
    __shared__ float sel[32][105];
    __shared__ float rd[32][105];
    __shared__ float red[32][12];
    int tid = threadIdx.x;
    int blk = blockIdx.x;
    for (int idx = tid; idx < 32 * 100; idx += 320) {
        int tt2 = idx / 100, d = idx % 100;
        int tok = blk * 32 + tt2;
        int b = tok >> 7;
        int hp = headi[tok] & 127;
        sel[tt2][d] = Hrh[((size_t)(b << 7) + hp) * 100 + d];
        rd[tt2][d] = Hrd[(size_t)tok * 100 + d];
    }
    __syncthreads();
    int tt2 = tid & 31;
    int dg = tid >> 5;   // 0..9
    int tok = blk * 32 + tt2;
    int r0 = blockIdx.y * 6;
    int r1 = min(46, r0 + 6);
    for (int r = r0; r < r1; ++r) {
        float acc = 0.f;
#pragma unroll
        for (int dd = 0; dd < 10; dd += 2) {
            int d = dg * 10 + dd;
            const float4* uA = (const float4*)(U + ((size_t)d * 46 + r) * 100);
            const float4* uB = (const float4*)(U + ((size_t)(d + 1) * 46 + r) * 100);
            float a0 = 0.f, a1 = 0.f, a2 = 0.f, a3 = 0.f;
            float b0 = 0.f, b1 = 0.f, b2 = 0.f, b3 = 0.f;
#pragma unroll
            for (int q = 0; q < 25; ++q) {
                float4 ua = uA[q], ub = uB[q];
                float r0v = rd[tt2][4 * q + 0], r1v = rd[tt2][4 * q + 1];
                float r2v = rd[tt2][4 * q + 2], r3v = rd[tt2][4 * q + 3];
                a0 = fmaf(ua.x, r0v, a0); a1 = fmaf(ua.y, r1v, a1);
                a2 = fmaf(ua.z, r2v, a2); a3 = fmaf(ua.w, r3v, a3);
                b0 = fmaf(ub.x, r0v, b0); b1 = fmaf(ub.y, r1v, b1);
                b2 = fmaf(ub.z, r2v, b2); b3 = fmaf(ub.w, r3v, b3);
            }
            acc = fmaf(sel[tt2][d], (a0 + a1) + (a2 + a3), acc);
            acc = fmaf(sel[tt2][d + 1], (b0 + b1) + (b2 + b3), acc);
        }
        if (dg == 0) {
            float sdot = 0.f;
#pragma unroll 4
            for (int k = 0; k < 100; ++k)
                sdot = fmaf(sel[tt2][k] + rd[tt2][k], Wrel[k * 46 + r], sdot);
            acc += sdot + brel[r];
        }
        red[tt2][dg] = acc;
        __syncthreads();
        if (dg == 0) {
            float tot = 0.f;
#pragma unroll
            for (int q = 0; q < 10; ++q) tot += red[tt2][q];
            out[(size_t)tok * 46 + r] = tot;
        }
        __syncthreads();
    }
}

// ---------------- launch ----------------
extern "C" void kernel_launch(void* const* d_in, const int* in_sizes, int n_in,
                              void* d_out, int out_size, void* d_ws, size_t ws_size,
                              hipStream_t stream) {
    const float* wemb = (const float*)d_in[0];
    const float* pemb = (const float*)d_in[1];
    const float* wi[3][2] = {{(const float*)d_in[2], (const float*)d_in[5]},
                             {(const float*)d_in[8], (const float*)d_in[11]},
                             {(const float*)d_in[14], (const float*)d_in[17]}};
    const float* wh[3][2] = {{(const float*)d_in[3], (const float*)d_in[6]},
                             {(const float*)d_in[9], (const float*)d_in[12]},
                             {(const float*)d_in[15], (const float*)d_in[18]}};
    const float* bia[3][2] = {{(const float*)d_in[4], (const float*)d_in[7]},
                              {(const float*)d_in[10], (const float*)d_in[13]},
                              {(const float*)d_in[16], (const float*)d_in[19]}};
    const float* Wad = (const float*)d_in[20]; const float* bad = (const float*)d_in[21];
    const float* Wah = (const float*)d_in[22]; const float* bah = (const float*)d_in[23];
    const float* Wrd = (const float*)d_in[24]; const float* brd = (const float*)d_in[25];
    const float* Wrh = (const float*)d_in[26]; const float* brh = (const float*)d_in[27];
    const float* Warc = (const float*)d_in[28]; const float* barc = (const float*)d_in[29];
    const float* U = (const float*)d_in[30];
    const float* Wrel = (const float*)d_in[31]; const float* brel = (const float*)d_in[32];
    const int* words = (const int*)d_in[33];
    const int* pos = (const int*)d_in[34];

    // ---- workspace (bytes); peak 133,005,312 ----
    char* ws = (char*)d_ws;
    double* hsA  = (double*)(ws + 0);
    double* hsB  = (double*)(ws + 52428800);
    float*  x0   = (float*)(ws + 52428800);      // aliases hsB (dead before layer 1)
    double* preF = (double*)(ws + 104857600);
    double* preB = (double*)(ws + 117964800);
    double* Hah64  = (double*)(ws + 52428800);
    double* Had64  = (double*)(ws + 85196800);
    float*  Hrh    = (float*)(ws + 117964800);
    float*  Hrd    = (float*)(ws + 121241600);
    double* S64    = (double*)(ws + 124518400);
    double* bh64   = (double*)(ws + 132907008);
    int*    headi  = (int*)(ws + 132972544);
    double* HadW64 = (double*)(ws + 0);          // over hsA (dead after head GEMMs)
    double* csF  = (double*)d_out;
    double* csB  = (double*)((char*)d_out + 204800);
    int*    flags = (int*)((char*)d_out + 409600);

    float* Sf = (float*)d_out;
    float* rel = Sf + 1048576;
    float* headf = Sf + 1425408;

    hipMemsetAsync(flags, 0, 768 * sizeof(int), stream);
    embed_k<<<NTOK, 128, 0, stream>>>(words, pos, wemb, pemb, x0);

    const size_t HALF = 3276800;   // doubles per direction (128*400*64)
    dim3 gPre(25, CH, 2);
    for (int l = 0; l < 3; ++l) {
        double* ho = (l == 1) ? hsB : hsA;
        const double* hiF = (l == 0) ? nullptr : ((l == 1) ? hsA : hsB);
        const double* hiB = hiF ? hiF + HALF : nullptr;
        for (int ci = 0; ci < 8; ++ci) {
            int m0F = ci * CH * 64;
            int m0B = (TT - CH - ci * CH) * 64;
            if (l == 0)
                pre_k<true><<<gPre, 256, 0, stream>>>(x0, nullptr, nullptr,
                    wi[0][0], wi[0][1], bia[0][0], bia[0][1], preF, preB, m0F, m0B);
            else
                pre_k<false><<<gPre, 256, 0, stream>>>(nullptr, hiF, hiB,
                    wi[l][0], wi[l][1], bia[l][0], bia[l][1], preF, preB, m0F, m0B);
            lstm_k<<<2 * NWD, 512, 0, stream>>>(preF, preB, wh[l][0], wh[l][1],
                ho, ho + HALF, csF, csB,
                flags + (l * 2 + 0) * 128, flags + (l * 2 + 1) * 128, ci);
        }
    }
    // heads from final h (hsA)
    const double* fF = hsA; const double* fB = hsA + HALF;
    heads_k<true, true, double><<<dim3(8, 128), 256, 0, stream>>>(
        nullptr, fF, fB, Wah, bah, Hah64, 500, 800, 500, 500, 1);
    heads_k<true, true, double><<<dim3(8, 128), 256, 0, stream>>>(
        nullptr, fF, fB, Wad, bad, Had64, 500, 800, 500, 500, 0);
    heads_k<true, true, float><<<dim3(2, 128), 256, 0, stream>>>(
        nullptr, fF, fB, Wrh, brh, Hrh, 100, 800, 100, 100, 1);
    heads_k<true, true, float><<<dim3(2, 128), 256, 0, stream>>>(
        nullptr, fF, fB, Wrd, brd, Hrd, 100, 800, 100, 100, 1);
    // hsA dead now; HadW64 aliases it
    heads_k<false, false, double><<<dim3(8, 128), 256, 0, stream>>>(
        Had64, nullptr, nullptr, Warc, nullptr, HadW64, 500, 500, 500, 500, 1);

    bh_k<<<NTOK / 4, 256, 0, stream>>>(Hah64, barc, bh64);
    s_k<<<dim3(8, 8, 64), dim3(16, 16), 0, stream>>>(HadW64, Hah64, bh64, S64, Sf);
    argmax_k<<<NTOK / 4, 256, 0, stream>>>(S64, headi, headf);
    rel_k<<<dim3(NTOK / 32, 8), 320, 0, stream>>>(Hrh, Hrd, headi, U, Wrel, brel, rel);
}

// Round 12
// 10626.818 us; speedup vs baseline: 10.8378x; 1.0788x over previous
//
#include <hip/hip_runtime.h>

// BiaffineParser round 12: round-11 base; ONLY change = wave0-only flag
// polling in lstm_k (8x fewer LLC pollers) + syncthreads release.

#define TT 128
#define HID 400
#define G4 1600
#define NTOK 8192
#define NWD 100     // workgroups per direction in lstm
#define CH 16       // timesteps per chunk

// ---------------- embedding concat (exact f32 copies) ----------------
__global__ void embed_k(const int* __restrict__ words, const int* __restrict__ pos,
                        const float* __restrict__ wemb, const float* __restrict__ pemb,
                        float* __restrict__ x0) {
    int m = blockIdx.x;            // m = t*64 + b
    int t = m >> 6, b = m & 63;
    int tid = threadIdx.x;
    if (tid < 100) {
        x0[(size_t)m * 125 + tid] = wemb[(size_t)words[b * TT + t] * 100 + tid];
    } else if (tid < 125) {
        x0[(size_t)m * 125 + tid] = pemb[(size_t)pos[b * TT + t] * 25 + (tid - 100)];
    }
}

// ---------------- dual-direction pre GEMM, 64x64 tiles, f64 (proven) ----------------
template <bool L0>
__global__ __launch_bounds__(256) void pre_k(
    const float* __restrict__ x0, const double* __restrict__ hF, const double* __restrict__ hB,
    const float* __restrict__ wiF, const float* __restrict__ wiB,
    const float* __restrict__ bF, const float* __restrict__ bB,
    double* __restrict__ prF, double* __restrict__ prB, int m0F, int m0B) {
    const int dir = blockIdx.z;
    const float* wi = dir ? wiB : wiF;
    const float* bias = dir ? bB : bF;
    double* pr = dir ? prB : prF;
    const int m0 = dir ? m0B : m0F;
    const int KP = L0 ? 128 : 800;

    __shared__ double As[16][66];   // [k][n]  <- wi
    __shared__ double Bs[16][66];   // [k][b]  <- h or x0

    const int tid = threadIdx.x;
    const int tm = tid >> 4, tn = tid & 15;
    const int bn = blockIdx.x * 64;
    const int y = blockIdx.y;
    const int tt = (m0 >> 6) + y;          // global timestep index
    const int lane = tid & 63, kq = tid >> 6;

    double acc[4][4];
#pragma unroll
    for (int i = 0; i < 4; i++)
#pragma unroll
        for (int j = 0; j < 4; j++) acc[i][j] = 0.0;

    for (int k0 = 0; k0 < KP; k0 += 16) {
        if (L0) {
#pragma unroll
            for (int u = 0; u < 4; u++) {
                int k = k0 + kq * 4 + u;
                As[kq * 4 + u][lane] = (k < 125) ? (double)wi[(size_t)(bn + lane) * 125 + k] : 0.0;
            }
        } else {
            const float4 wv = *(const float4*)&wi[(size_t)(bn + lane) * 800 + k0 + kq * 4];
            As[kq * 4 + 0][lane] = (double)wv.x;
            As[kq * 4 + 1][lane] = (double)wv.y;
            As[kq * 4 + 2][lane] = (double)wv.z;
            As[kq * 4 + 3][lane] = (double)wv.w;
        }
        if (L0) {
#pragma unroll
            for (int u = 0; u < 4; u++) {
                int k = k0 + kq * 4 + u;
                Bs[kq * 4 + u][lane] = (k < 125) ? (double)x0[((size_t)tt * 64 + lane) * 125 + k] : 0.0;
            }
        } else {
            int kbase = k0 + kq * 4;                // blocks of 4, never straddle 400
            const double* src = (kbase < 400) ? hF : hB;
            int kb = (kbase < 400) ? kbase : kbase - 400;
            const double* p = src + (size_t)tt * 25600 + (size_t)kb * 64 + lane;
#pragma unroll
            for (int u = 0; u < 4; u++) Bs[kq * 4 + u][lane] = p[(size_t)u * 64];
        }
        __syncthreads();
#pragma unroll
        for (int kk = 0; kk < 16; kk++) {
            double a[4], b[4];
#pragma unroll
            for (int i = 0; i < 4; i++) a[i] = As[kk][tm * 4 + i];
#pragma unroll
            for (int j = 0; j < 4; j++) b[j] = Bs[kk][tn * 4 + j];
#pragma unroll
            for (int i = 0; i < 4; i++)
#pragma unroll
                for (int j = 0; j < 4; j++) acc[i][j] = fma(a[i], b[j], acc[i][j]);
        }
        __syncthreads();
    }
#pragma unroll
    for (int i = 0; i < 4; i++) {
        int n = bn + tm * 4 + i;
        double bv = (double)bias[n];
#pragma unroll
        for (int j = 0; j < 4; j++)
            pr[((size_t)y * G4 + n) * 64 + (tn * 4 + j)] = acc[i][j] + bv;
    }
}

// ---------------- heads GEMM, 64x64 tiles, f64 accumulate (proven) ----------------
template <bool SPLITA, bool RELU, typename TC>
__global__ __launch_bounds__(256) void heads_k(
    const double* __restrict__ A, const double* __restrict__ AF, const double* __restrict__ AB,
    const float* __restrict__ Bm, const float* __restrict__ bias, TC* __restrict__ C,
    int N, int K, int ldb, int ldc, int OM) {
    __shared__ double As[16][66];   // [k][m]
    __shared__ double Bs[16][66];   // [k][n]
    const int tid = threadIdx.x;
    const int tm = tid >> 4, tn = tid & 15;
    const int bn = blockIdx.x * 64;
    const int bm = blockIdx.y * 64;
    const int lane = tid & 63, kq = tid >> 6;

    double acc[4][4];
#pragma unroll
    for (int i = 0; i < 4; i++)
#pragma unroll
        for (int j = 0; j < 4; j++) acc[i][j] = 0.0;

    const int KP = (K + 15) & ~15;
    for (int k0 = 0; k0 < KP; k0 += 16) {
        if (SPLITA) {
            int kbase = k0 + kq * 4;
            const double* src = (kbase < 400) ? AF : AB;
            int kb = (kbase < 400) ? kbase : kbase - 400;
            const double* p = src + (size_t)(bm >> 6) * 25600 + (size_t)kb * 64 + lane;
#pragma unroll
            for (int u = 0; u < 4; u++) As[kq * 4 + u][lane] = p[(size_t)u * 64];
        } else {
#pragma unroll
            for (int u = 0; u < 4; u++) {
                int k = k0 + kq * 4 + u;
                As[kq * 4 + u][lane] = (k < K) ? A[(size_t)(bm + lane) * K + k] : 0.0;
            }
        }
        {
            bool nok = (bn + lane) < N;
#pragma unroll
            for (int u = 0; u < 4; u++) {
                int k = k0 + kq * 4 + u;
                Bs[kq * 4 + u][lane] = (nok && k < K) ? (double)Bm[(size_t)k * ldb + bn + lane] : 0.0;
            }
        }
        __syncthreads();
#pragma unroll
        for (int kk = 0; kk < 16; kk++) {
            double a[4], b[4];
#pragma unroll
            for (int i = 0; i < 4; i++) a[i] = As[kk][tm * 4 + i];
#pragma unroll
            for (int j = 0; j < 4; j++) b[j] = Bs[kk][tn * 4 + j];
#pragma unroll
            for (int i = 0; i < 4; i++)
#pragma unroll
                for (int j = 0; j < 4; j++) acc[i][j] = fma(a[i], b[j], acc[i][j]);
        }
        __syncthreads();
    }
#pragma unroll
    for (int i = 0; i < 4; i++) {
        int row = bm + tm * 4 + i;
        size_t orow = (OM == 0) ? (size_t)row
                                : ((size_t)(row & 63) * TT + (row >> 6));
#pragma unroll
        for (int j = 0; j < 4; j++) {
            int n = bn + tn * 4 + j;
            if (n >= N) continue;
            double v = acc[i][j] + (bias ? (double)bias[n] : 0.0);
            if (RELU) v = fmax(v, 0.0);
            C[orow * ldc + n] = (TC)v;
        }
    }
}

// ---------------- both-direction LSTM chunk (f64), wave0-only flag poll ----
__global__ __launch_bounds__(512) void lstm_k(
    const double* __restrict__ preF, const double* __restrict__ preB,
    const float* __restrict__ whF, const float* __restrict__ whB,
    double* __restrict__ hsF, double* __restrict__ hsB,
    double* __restrict__ csF, double* __restrict__ csB,
    int* __restrict__ flagsF, int* __restrict__ flagsB, int ci) {
    const int wg = blockIdx.x;
    const int dir = wg / NWD;
    const int wgd = wg % NWD;
    const double* pre = dir ? preB : preF;
    const float* wh = dir ? whB : whF;
    double* hs = dir ? hsB : hsF;
    double* cs = dir ? csB : csF;
    int* flags = dir ? flagsB : flagsF;
    const int tid = threadIdx.x;
    const int b = tid & 63;
    const int w = tid >> 6;
    const int tlb = dir ? (TT - CH - ci * CH) : ci * CH;

    __shared__ double whl[4][HID][4];
    __shared__ double pl[8][4][4][64];
    for (int idx = tid; idx < 4 * HID * 4; idx += 512) {
        int g = idx & 3; int k = (idx >> 2) % HID; int jx = idx / (4 * HID);
        whl[jx][k][g] = (double)wh[((size_t)g * HID + wgd * 4 + jx) * HID + k];
    }
    __syncthreads();

    const int jown = wgd * 4 + (w & 3);
    double c = 0.0;
    if (w < 4) c = (ci == 0) ? 0.0 : cs[(size_t)jown * 64 + b];

    for (int s = 0; s < CH; ++s) {
        const int sg = ci * CH + s;
        const int t = dir ? (TT - 1 - sg) : sg;
        // pre loads independent of h: issue before the poll
        double z0[4];
        if (w < 4) {
            const double* pp = pre + (size_t)(t - tlb) * (G4 * 64) + b;
#pragma unroll
            for (int g = 0; g < 4; g++) z0[g] = pp[(size_t)(g * HID + jown) * 64];
        }
        if (sg > 0) {
            if (w == 0) {   // ONE wave polls; 8x fewer LLC requests
                bool need2 = b < (NWD - 64);
                for (;;) {
                    int f1 = __hip_atomic_load(&flags[b], __ATOMIC_RELAXED, __HIP_MEMORY_SCOPE_AGENT);
                    int f2 = need2 ? __hip_atomic_load(&flags[64 + b], __ATOMIC_RELAXED, __HIP_MEMORY_SCOPE_AGENT)
                                   : 0x7fffffff;
                    if (__all(f1 >= sg && f2 >= sg)) break;
                    __builtin_amdgcn_s_sleep(1);
                }
                __builtin_amdgcn_fence(__ATOMIC_ACQUIRE, "agent");
            }
            __syncthreads();   // release the other 7 waves
        }
        double part[4][4];
#pragma unroll
        for (int j = 0; j < 4; j++)
#pragma unroll
            for (int g = 0; g < 4; g++) part[j][g] = 0.0;
        if (sg > 0) {
            const int tp = dir ? (t + 1) : (t - 1);
            const double* hp = hs + (size_t)tp * (HID * 64) + b;
#pragma unroll 5
            for (int k = w * 50; k < w * 50 + 50; ++k) {
                double hv = hp[(size_t)k * 64];     // plain cached load (fresh by construction)
#pragma unroll
                for (int j = 0; j < 4; j++)
#pragma unroll
                    for (int g = 0; g < 4; g++)
                        part[j][g] = fma(hv, whl[j][k][g], part[j][g]);
            }
        }
#pragma unroll
        for (int j = 0; j < 4; j++)
#pragma unroll
            for (int g = 0; g < 4; g++) pl[w][j][g][b] = part[j][g];
        __syncthreads();
        if (w < 4) {
            double z[4];
#pragma unroll
            for (int g = 0; g < 4; g++) {
                double acc = z0[g];
#pragma unroll
                for (int q = 0; q < 8; q++) acc += pl[q][w][g][b];
                z[g] = acc;
            }
            double si = 1.0 / (1.0 + exp(-z[0]));
            double sf = 1.0 / (1.0 + exp(-z[1]));
            double tg = tanh(z[2]);
            double so = 1.0 / (1.0 + exp(-z[3]));
            c = sf * c + si * tg;
            double h = so * tanh(c);
            __hip_atomic_store(&hs[(size_t)t * (HID * 64) + (size_t)jown * 64 + b], h,
                               __ATOMIC_RELAXED, __HIP_MEMORY_SCOPE_AGENT);
        }
        __syncthreads();   // drains h stores (vmcnt0) + pl reuse guard
        if (tid == 0)
            __hip_atomic_store(&flags[wgd], sg + 1, __ATOMIC_RELEASE, __HIP_MEMORY_SCOPE_AGENT);
    }
    if (w < 4) cs[(size_t)jown * 64 + b] = c;
}

// ---------------- b_arc . H_ah[b,j] (f64) ----------------
__global__ void bh_k(const double* __restrict__ Hah, const float* __restrict__ barc,
                     double* __restrict__ bh) {
    int row = blockIdx.x * 4 + (threadIdx.x >> 6);
    int lane = threadIdx.x & 63;
    const double* r = Hah + (size_t)row * 500;
    double s = 0.0;
    for (int e = lane; e < 500; e += 64) s = fma(r[e], (double)barc[e], s);
    for (int off = 32; off; off >>= 1) s += __shfl_down(s, off, 64);
    if (lane == 0) bh[row] = s;
}

// ---------------- biaffine scores (f64), write S64 + f32 S ----------------
__global__ __launch_bounds__(256) void s_k(const double* __restrict__ HadW,
                                           const double* __restrict__ Hah,
                                           const double* __restrict__ bh,
                                           double* __restrict__ S64,
                                           float* __restrict__ Sf) {
    int b = blockIdx.z;
    int i = blockIdx.y * 16 + threadIdx.y;
    int j = blockIdx.x * 16 + threadIdx.x;
    const double* ra = HadW + ((size_t)b * TT + i) * 500;
    const double* rb = Hah + ((size_t)b * TT + j) * 500;
    double s = 0.0;
#pragma unroll 4
    for (int e = 0; e < 500; ++e) s = fma(ra[e], rb[e], s);
    double v = s + bh[b * TT + j];
    size_t o = ((size_t)b * TT + i) * TT + j;
    S64[o] = v;
    Sf[o] = (float)v;
}

// ---------------- argmax with near-tie window, first-index pref ----------------
__global__ void argmax_k(const double* __restrict__ S64, int* __restrict__ headi,
                         float* __restrict__ headf) {
    int row = blockIdx.x * 4 + (threadIdx.x >> 6);
    int lane = threadIdx.x & 63;
    const double* r = S64 + (size_t)row * TT;
    double v0 = r[lane], v1 = r[lane + 64];
    double m = fmax(v0, v1);
    for (int off = 32; off; off >>= 1) m = fmax(m, __shfl_down(m, off, 64));
    m = __shfl(m, 0, 64);
    double tau = 1e-4 + 3e-6 * fabs(m);
    int c = 999;
    if (v1 >= m - tau) c = lane + 64;
    if (v0 >= m - tau) c = lane;
    for (int off = 32; off; off >>= 1) {
        int oc = __shfl_down(c, off, 64);
        c = min(c, oc);
    }
    if (lane == 0) { headi[row] = c; headf[row] = (float)c; }
}

// ---------------- rel scores: f32, 8-chain ILP, r-split x8 ----------------
__global__ __launch_bounds__(320) void rel_k(
    const float* __restrict__ Hrh, const float* __restrict__ Hrd,
    const int* __restrict__ headi, const float* __restrict__ U,
    const float* __restrict__ Wrel, const float* __restrict__ brel,
    float* __restrict__ out) {
    __shared__ float sel[32][105];
    __shared__ float rd[32][105];
    __shared__ float red[32][12];
    int tid = threadIdx.x;
    int blk = blockIdx.x;
    for (int idx = tid; idx < 32 * 100; idx += 320) {
        int tt2 = idx / 100, d = idx % 100;
        int tok = blk * 32 + tt2;
        int b = tok >> 7;
        int hp = headi[tok] & 127;
        sel[tt2][d] = Hrh[((size_t)(b << 7) + hp) * 100 + d];
        rd[tt2][d] = Hrd[(size_t)tok * 100 + d];
    }
    __syncthreads();
    int tt2 = tid & 31;
    int dg = tid >> 5;   // 0..9
    int tok = blk * 32 + tt2;
    int r0 = blockIdx.y * 6;
    int r1 = min(46, r0 + 6);
    for (int r = r0; r < r1; ++r) {
        float acc = 0.f;
#pragma unroll
        for (int dd = 0; dd < 10; dd += 2) {
            int d = dg * 10 + dd;
            const float4* uA = (const float4*)(U + ((size_t)d * 46 + r) * 100);
            const float4* uB = (const float4*)(U + ((size_t)(d + 1) * 46 + r) * 100);
            float a0 = 0.f, a1 = 0.f, a2 = 0.f, a3 = 0.f;
            float b0 = 0.f, b1 = 0.f, b2 = 0.f, b3 = 0.f;
#pragma unroll
            for (int q = 0; q < 25; ++q) {
                float4 ua = uA[q], ub = uB[q];
                float r0v = rd[tt2][4 * q + 0], r1v = rd[tt2][4 * q + 1];
                float r2v = rd[tt2][4 * q + 2], r3v = rd[tt2][4 * q + 3];
                a0 = fmaf(ua.x, r0v, a0); a1 = fmaf(ua.y, r1v, a1);
                a2 = fmaf(ua.z, r2v, a2); a3 = fmaf(ua.w, r3v, a3);
                b0 = fmaf(ub.x, r0v, b0); b1 = fmaf(ub.y, r1v, b1);
                b2 = fmaf(ub.z, r2v, b2); b3 = fmaf(ub.w, r3v, b3);
            }
            acc = fmaf(sel[tt2][d], (a0 + a1) + (a2 + a3), acc);
            acc = fmaf(sel[tt2][d + 1], (b0 + b1) + (b2 + b3), acc);
        }
        if (dg == 0) {
            float sdot = 0.f;
#pragma unroll 4
            for (int k = 0; k < 100; ++k)
                sdot = fmaf(sel[tt2][k] + rd[tt2][k], Wrel[k * 46 + r], sdot);
            acc += sdot + brel[r];
        }
        red[tt2][dg] = acc;
        __syncthreads();
        if (dg == 0) {
            float tot = 0.f;
#pragma unroll
            for (int q = 0; q < 10; ++q) tot += red[tt2][q];
            out[(size_t)tok * 46 + r] = tot;
        }
        __syncthreads();
    }
}

// ---------------- launch ----------------
extern "C" void kernel_launch(void* const* d_in, const int* in_sizes, int n_in,
                              void* d_out, int out_size, void* d_ws, size_t ws_size,
                              hipStream_t stream) {
    const float* wemb = (const float*)d_in[0];
    const float* pemb = (const float*)d_in[1];
    const float* wi[3][2] = {{(const float*)d_in[2], (const float*)d_in[5]},
                             {(const float*)d_in[8], (const float*)d_in[11]},
                             {(const float*)d_in[14], (const float*)d_in[17]}};
    const float* wh[3][2] = {{(const float*)d_in[3], (const float*)d_in[6]},
                             {(const float*)d_in[9], (const float*)d_in[12]},
                             {(const float*)d_in[15], (const float*)d_in[18]}};
    const float* bia[3][2] = {{(const float*)d_in[4], (const float*)d_in[7]},
                              {(const float*)d_in[10], (const float*)d_in[13]},
                              {(const float*)d_in[16], (const float*)d_in[19]}};
    const float* Wad = (const float*)d_in[20]; const float* bad = (const float*)d_in[21];
    const float* Wah = (const float*)d_in[22]; const float* bah = (const float*)d_in[23];
    const float* Wrd = (const float*)d_in[24]; const float* brd = (const float*)d_in[25];
    const float* Wrh = (const float*)d_in[26]; const float* brh = (const float*)d_in[27];
    const float* Warc = (const float*)d_in[28]; const float* barc = (const float*)d_in[29];
    const float* U = (const float*)d_in[30];
    const float* Wrel = (const float*)d_in[31]; const float* brel = (const float*)d_in[32];
    const int* words = (const int*)d_in[33];
    const int* pos = (const int*)d_in[34];

    // ---- workspace (bytes); peak 133,005,312 ----
    char* ws = (char*)d_ws;
    double* hsA  = (double*)(ws + 0);
    double* hsB  = (double*)(ws + 52428800);
    float*  x0   = (float*)(ws + 52428800);      // aliases hsB (dead before layer 1)
    double* preF = (double*)(ws + 104857600);
    double* preB = (double*)(ws + 117964800);
    double* Hah64  = (double*)(ws + 52428800);
    double* Had64  = (double*)(ws + 85196800);
    float*  Hrh    = (float*)(ws + 117964800);
    float*  Hrd    = (float*)(ws + 121241600);
    double* S64    = (double*)(ws + 124518400);
    double* bh64   = (double*)(ws + 132907008);
    int*    headi  = (int*)(ws + 132972544);
    double* HadW64 = (double*)(ws + 0);          // over hsA (dead after head GEMMs)
    double* csF  = (double*)d_out;
    double* csB  = (double*)((char*)d_out + 204800);
    int*    flags = (int*)((char*)d_out + 409600);

    float* Sf = (float*)d_out;
    float* rel = Sf + 1048576;
    float* headf = Sf + 1425408;

    hipMemsetAsync(flags, 0, 768 * sizeof(int), stream);
    embed_k<<<NTOK, 128, 0, stream>>>(words, pos, wemb, pemb, x0);

    const size_t HALF = 3276800;   // doubles per direction (128*400*64)
    dim3 gPre(25, CH, 2);
    for (int l = 0; l < 3; ++l) {
        double* ho = (l == 1) ? hsB : hsA;
        const double* hiF = (l == 0) ? nullptr : ((l == 1) ? hsA : hsB);
        const double* hiB = hiF ? hiF + HALF : nullptr;
        for (int ci = 0; ci < 8; ++ci) {
            int m0F = ci * CH * 64;
            int m0B = (TT - CH - ci * CH) * 64;
            if (l == 0)
                pre_k<true><<<gPre, 256, 0, stream>>>(x0, nullptr, nullptr,
                    wi[0][0], wi[0][1], bia[0][0], bia[0][1], preF, preB, m0F, m0B);
            else
                pre_k<false><<<gPre, 256, 0, stream>>>(nullptr, hiF, hiB,
                    wi[l][0], wi[l][1], bia[l][0], bia[l][1], preF, preB, m0F, m0B);
            lstm_k<<<2 * NWD, 512, 0, stream>>>(preF, preB, wh[l][0], wh[l][1],
                ho, ho + HALF, csF, csB,
                flags + (l * 2 + 0) * 128, flags + (l * 2 + 1) * 128, ci);
        }
    }
    // heads from final h (hsA)
    const double* fF = hsA; const double* fB = hsA + HALF;
    heads_k<true, true, double><<<dim3(8, 128), 256, 0, stream>>>(
        nullptr, fF, fB, Wah, bah, Hah64, 500, 800, 500, 500, 1);
    heads_k<true, true, double><<<dim3(8, 128), 256, 0, stream>>>(
        nullptr, fF, fB, Wad, bad, Had64, 500, 800, 500, 500, 0);
    heads_k<true, true, float><<<dim3(2, 128), 256, 0, stream>>>(
        nullptr, fF, fB, Wrh, brh, Hrh, 100, 800, 100, 100, 1);
    heads_k<true, true, float><<<dim3(2, 128), 256, 0, stream>>>(
        nullptr, fF, fB, Wrd, brd, Hrd, 100, 800, 100, 100, 1);
    // hsA dead now; HadW64 aliases it
    heads_k<false, false, double><<<dim3(8, 128), 256, 0, stream>>>(
        Had64, nullptr, nullptr, Warc, nullptr, HadW64, 500, 500, 500, 500, 1);

    bh_k<<<NTOK / 4, 256, 0, stream>>>(Hah64, barc, bh64);
    s_k<<<dim3(8, 8, 64), dim3(16, 16), 0, stream>>>(HadW64, Hah64, bh64, S64, Sf);
    argmax_k<<<NTOK / 4, 256, 0, stream>>>(S64, headi, headf);
    rel_k<<<dim3(NTOK / 32, 8), 320, 0, stream>>>(Hrh, Hrd, headi, U, Wrel, brel, rel);
}